// Round 9
// baseline (189.065 us; speedup 1.0000x reference)
//
#include <hip/hip_runtime.h>
#include <hip/hip_bf16.h>

// Sizes for this problem
#define T_SEQ 4096
#define C_DIM 1024
#define NH    16
#define HD    64
#define C3    3072

typedef __attribute__((ext_vector_type(8))) short short8;
typedef __attribute__((ext_vector_type(4))) short short4v;
typedef __attribute__((ext_vector_type(4))) float f32x4;
typedef __attribute__((ext_vector_type(16))) float f32x16;

__device__ __forceinline__ short f2bf(float f) {
  union { float f; unsigned u; } v; v.f = f;
  unsigned r = v.u + 0x7FFFu + ((v.u >> 16) & 1u);   // round-to-nearest-even
  return (short)(r >> 16);
}

__device__ __forceinline__ unsigned cvt_pk_bf16(float lo, float hi) {
  unsigned r;
  asm volatile("v_cvt_pk_bf16_f32 %0, %1, %2" : "=v"(r) : "v"(lo), "v"(hi));
  return r;
}

// single-instruction 2^x (exp2f w/o fast-math is a multi-inst ocml call)
__device__ __forceinline__ float exp2_fast(float x) {
  return __builtin_amdgcn_exp2f(x);
}

// cross-half (lane^32) reduces via ds_bpermute-based shfl (proven correct here;
// permlane32_swap-based reduce failed twice — suspected wait-state hazard).
__device__ __forceinline__ float max_half64(float v) {
  return fmaxf(v, __shfl_xor(v, 32, 64));
}
__device__ __forceinline__ float sum_half64(float v) {
  return v + __shfl_xor(v, 32, 64);
}

__device__ __forceinline__ float m3(float a, float b, float c) {
  return fmaxf(fmaxf(a, b), c);   // clang fuses to v_max3_f32
}

__device__ __forceinline__ void gld_lds16(const void* g, void* l) {
  __builtin_amdgcn_global_load_lds(
      (const __attribute__((address_space(1))) unsigned int*)g,
      (__attribute__((address_space(3))) unsigned int*)l, 16, 0, 0);
}

// ---------------- fp32 -> bf16 convert (x) ----------------
__global__ __launch_bounds__(256) void conv_bf16_kernel(const float* __restrict__ in,
                                                        short* __restrict__ out) {
  const size_t i = ((size_t)blockIdx.x * 256 + threadIdx.x) * 8;
  float4 v0 = *(const float4*)(in + i);
  float4 v1 = *(const float4*)(in + i + 4);
  short8 o;
  o[0] = f2bf(v0.x); o[1] = f2bf(v0.y); o[2] = f2bf(v0.z); o[3] = f2bf(v0.w);
  o[4] = f2bf(v1.x); o[5] = f2bf(v1.y); o[6] = f2bf(v1.z); o[7] = f2bf(v1.w);
  *(short8*)(out + i) = o;
}

// ---------------- fp32 [K][N] -> bf16 [N][K] transpose-convert ----------------
__global__ void trans_conv_kernel(const float* __restrict__ in, short* __restrict__ out,
                                  int K, int N) {
  __shared__ float t[32][33];
  const int n0 = blockIdx.x * 32, k0 = blockIdx.y * 32;
  const int tx = threadIdx.x, ty = threadIdx.y;
  for (int i = ty; i < 32; i += 8) t[i][tx] = in[(size_t)(k0 + i) * N + n0 + tx];
  __syncthreads();
  for (int i = ty; i < 32; i += 8) out[(size_t)(n0 + i) * K + k0 + tx] = f2bf(t[tx][i]);
}

// ---------------- bf16 GEMM: C[M,N] = A[M,K] * BT[N,K]^T ----------------
__device__ __forceinline__ void store_out(short* C, size_t idx, float v) { C[idx] = f2bf(v); }
__device__ __forceinline__ void store_out(float* C, size_t idx, float v) { C[idx] = v; }

template <typename OutT>
__global__ __launch_bounds__(256) void gemm_bt_kernel(const short* __restrict__ A,
                                                      const short* __restrict__ BT,
                                                      OutT* __restrict__ C,
                                                      int M, int N, int K) {
  __shared__ __align__(16) short As[128 * 32];
  __shared__ __align__(16) short Bs[128 * 32];
  const int tid = threadIdx.x;
  const int wid = tid >> 6;
  const int lane = tid & 63;
  const int l15 = lane & 15;
  const int l4 = lane >> 4;
  const int wr = wid >> 1;
  const int wc = wid & 1;
  const int bm = blockIdx.y * 128;
  const int bn = blockIdx.x * 128;

  f32x4 acc[4][4];
#pragma unroll
  for (int m = 0; m < 4; ++m)
#pragma unroll
    for (int n = 0; n < 4; ++n) acc[m][n] = (f32x4){0.f, 0.f, 0.f, 0.f};

  const int ebase = wid * 1024;              // 1024 bf16 elements per wave (2 x 512)
  const int e0 = ebase + lane * 8;
  const int r0 = e0 >> 5, c0 = e0 & 31;
  const int r1 = r0 + 16;                    // e0 + 512

  for (int k0 = 0; k0 < K; k0 += 32) {
    __syncthreads();
    gld_lds16(A + (size_t)(bm + r0) * K + k0 + c0, As + ebase);
    gld_lds16(A + (size_t)(bm + r1) * K + k0 + c0, As + ebase + 512);
    gld_lds16(BT + (size_t)(bn + r0) * K + k0 + c0, Bs + ebase);
    gld_lds16(BT + (size_t)(bn + r1) * K + k0 + c0, Bs + ebase + 512);
    __syncthreads();

    short8 a[4], b[4];
#pragma unroll
    for (int m = 0; m < 4; ++m)
      a[m] = *(const short8*)&As[(wr * 64 + m * 16 + l15) * 32 + l4 * 8];
#pragma unroll
    for (int n = 0; n < 4; ++n)
      b[n] = *(const short8*)&Bs[(wc * 64 + n * 16 + l15) * 32 + l4 * 8];
#pragma unroll
    for (int m = 0; m < 4; ++m)
#pragma unroll
      for (int n = 0; n < 4; ++n)
        acc[m][n] = __builtin_amdgcn_mfma_f32_16x16x32_bf16(a[m], b[n], acc[m][n], 0, 0, 0);
  }

#pragma unroll
  for (int m = 0; m < 4; ++m) {
    const int row0 = bm + wr * 64 + m * 16 + l4 * 4;
#pragma unroll
    for (int n = 0; n < 4; ++n) {
      const int col = bn + wc * 64 + n * 16 + l15;
#pragma unroll
      for (int r = 0; r < 4; ++r)
        store_out(C, (size_t)(row0 + r) * N + col, acc[m][n][r]);
    }
  }
}

// ---------------- repack V: qkv[t][2048 + h*64 + d] -> vT[h][d][t] ----------------
__global__ __launch_bounds__(256) void repack_v_kernel(const short* __restrict__ qkv,
                                                       short* __restrict__ vT) {
  const int h = blockIdx.x >> 6;
  const int t0 = (blockIdx.x & 63) << 6;
  __shared__ __align__(16) short tile[64][72];
  const int t = threadIdx.x;
  const int r = t >> 3, c = (t & 7) << 3;
#pragma unroll
  for (int i = 0; i < 2; ++i) {
    const int rr = r + i * 32;
    *(short8*)&tile[rr][c] =
        *(const short8*)&qkv[(size_t)(t0 + rr) * C3 + 2048 + h * 64 + c];
  }
  __syncthreads();
  const int d = t >> 3, tt = (t & 7) << 3;
#pragma unroll
  for (int i = 0; i < 2; ++i) {
    const int dd = d + i * 32;
    short8 v;
#pragma unroll
    for (int j = 0; j < 8; ++j) v[j] = tile[tt + j][dd];
    *(short8*)&vT[(size_t)(h * 64 + dd) * T_SEQ + t0 + tt] = v;
  }
}

// ---------------- flash attention: independent 4-wave blocks per KV half ----------------
// 1024 blocks x 256 threads: (head, half, q-block of 128). Each wave: 32 q-rows.
// Writes unnormalized O + (m,l) partials; merge_kernel combines the two halves.
__global__ __launch_bounds__(256, 4) void attn_kernel(const short* __restrict__ qkv,
                                                      const short* __restrict__ vT,
                                                      float* __restrict__ Opart,
                                                      float* __restrict__ MLpart) {
  // XCD-aware: 32 (head,half) streams, 4 per XCD -> per-XCD KV working set 2 MB
  const int bid = blockIdx.x;
  const int xcd = bid & 7, rest = bid >> 3;        // rest 0..127
  const int s = xcd * 4 + (rest >> 5);             // stream 0..31
  const int h = s >> 1, half = s & 1;
  const int q0 = (rest & 31) * 128;
  const int kvbase = half * (T_SEQ / 2);

  const int tid = threadIdx.x;
  const int w = tid >> 6, lane = tid & 63, l31 = lane & 31, l1 = lane >> 5;

  __shared__ __align__(16) short Ks[2][4096];   // [dbuf][kv*64+d], d-swizzled
  __shared__ __align__(16) short Vs[2][4096];   // [dbuf][d*64+kv], kv-swizzled

  // Q B-fragments: col q = l31, k = d = ks*16 + l1*8 + j
  short8 qf[4];
  {
    const short* qp = qkv + (size_t)(q0 + w * 32 + l31) * C3 + h * 64 + l1 * 8;
#pragma unroll
    for (int ks = 0; ks < 4; ++ks) qf[ks] = *(const short8*)(qp + ks * 16);
  }

  f32x16 oa0, oa1;   // O^T: col q=l31, row d=(r&3)+8*(r>>2)+4*l1 (+32 for oa1)
#pragma unroll
  for (int r = 0; r < 16; ++r) { oa0[r] = 0.f; oa1[r] = 0.f; }
  float m_r = -INFINITY, l_r = 0.f;
  const float SCL = 0.125f * 1.44269504f;          // 1/sqrt(64) * log2(e)
  const float TH = 8.0f / SCL;                     // defer-max threshold (p <= 2^8)

  // staging: row lr0 = w*8 + (lane>>3) (+32 for i=1), source col pre-swizzled
  const int lr0 = w * 8 + (lane >> 3);
  const int csw = ((lane & 7) << 3) ^ ((lane >> 3) << 3);   // shorts
  const short* kpt = qkv + 1024 + h * 64 + csw + (size_t)(kvbase + lr0) * C3;
  const short* vpt = vT + (size_t)(h * 64 + lr0) * T_SEQ + csw + kvbase;
  const int rswz = (l31 & 7) << 3;

  auto stage = [&](int buf) {
#pragma unroll
    for (int i = 0; i < 2; ++i) {
      gld_lds16(kpt + (size_t)i * 32 * C3, &Ks[buf][i * 2048 + w * 512]);
      gld_lds16(vpt + (size_t)i * 32 * T_SEQ, &Vs[buf][i * 2048 + w * 512]);
    }
  };

  stage(0);
  kpt += (size_t)64 * C3;
  vpt += 64;

  const int NT = T_SEQ / 2 / 64;   // 32 tiles per half
  for (int t = 0; t < NT; ++t) {
    const int cur = t & 1;
    // barrier 1: everyone done READING buf cur^1 -> safe to overwrite
    __builtin_amdgcn_s_barrier();
    if (t + 1 < NT) {
      stage(cur ^ 1);
      kpt += (size_t)64 * C3;
      vpt += 64;
      asm volatile("s_waitcnt vmcnt(4)" ::: "memory");   // tile t's 4 loads landed; t+1's fly
    } else {
      asm volatile("s_waitcnt vmcnt(0)" ::: "memory");   // last tile: full drain
    }
    // barrier 2: everyone's tile-t data is in LDS
    __builtin_amdgcn_s_barrier();

    const short* Kb = &Ks[cur][0];
    const short* Vb = &Vs[cur][0];

    // S^T = K Q^T: two 32-kv subtiles
    f32x16 s0, s1;
#pragma unroll
    for (int r = 0; r < 16; ++r) { s0[r] = 0.f; s1[r] = 0.f; }
    __builtin_amdgcn_s_setprio(1);
#pragma unroll
    for (int ks = 0; ks < 4; ++ks) {
      const int c = (ks * 16 + l1 * 8) ^ rswz;
      short8 k0 = *(const short8*)&Kb[l31 * 64 + c];
      short8 k1 = *(const short8*)&Kb[(32 + l31) * 64 + c];
      s0 = __builtin_amdgcn_mfma_f32_32x32x16_bf16(k0, qf[ks], s0, 0, 0, 0);
      s1 = __builtin_amdgcn_mfma_f32_32x32x16_bf16(k1, qf[ks], s1, 0, 0, 0);
    }
    __builtin_amdgcn_s_setprio(0);

    // tile max via max3-shaped tree (v_max3_f32)
    float tm;
    {
      float v0 = m3(s0[0], s0[1], s0[2]);
      float v1 = m3(s0[3], s0[4], s0[5]);
      float v2 = m3(s0[6], s0[7], s0[8]);
      float v3 = m3(s0[9], s0[10], s0[11]);
      float v4 = m3(s0[12], s0[13], s0[14]);
      float v5 = fmaxf(s0[15], s1[0]);
      float v6 = m3(s1[1], s1[2], s1[3]);
      float v7 = m3(s1[4], s1[5], s1[6]);
      float v8 = m3(s1[7], s1[8], s1[9]);
      float v9 = m3(s1[10], s1[11], s1[12]);
      float v10 = m3(s1[13], s1[14], s1[15]);
      float w0 = m3(v0, v1, v2);
      float w1 = m3(v3, v4, v5);
      float w2 = m3(v6, v7, v8);
      float w3 = fmaxf(v9, v10);
      tm = fmaxf(m3(w0, w1, w2), w3);
    }
    tm = max_half64(tm);

    if (__any(tm > m_r + TH)) {            // defer-max: skip rescale on stable tiles
      const float mn = fmaxf(m_r, tm);
      const float al = exp2_fast((m_r - mn) * SCL);
      m_r = mn;
      l_r *= al;
#pragma unroll
      for (int r = 0; r < 16; ++r) { oa0[r] *= al; oa1[r] *= al; }
    }
    const float msc = m_r * SCL;
#pragma unroll
    for (int r = 0; r < 16; ++r) s0[r] = exp2_fast(fmaf(s0[r], SCL, -msc));
#pragma unroll
    for (int r = 0; r < 16; ++r) s1[r] = exp2_fast(fmaf(s1[r], SCL, -msc));

    // row-sum via tree
    float ps;
    {
      float u8[8];
#pragma unroll
      for (int r = 0; r < 8; ++r)
        u8[r] = (s0[r] + s0[r + 8]) + (s1[r] + s1[r + 8]);
#pragma unroll
      for (int r = 0; r < 4; ++r) u8[r] += u8[r + 4];
      ps = (u8[0] + u8[2]) + (u8[1] + u8[3]);
    }
    ps = sum_half64(ps);
    l_r += ps;

    // P -> B-fragments in-register: cvt_pk + permlane32_swap (T12).
    // s_nop guards the VALU-write->permlane-read wait-state hazard (opaque to compiler).
    unsigned pw[4][4];
#pragma unroll
    for (int half2 = 0; half2 < 2; ++half2) {
      const f32x16& sv = half2 ? s1 : s0;
#pragma unroll
      for (int kk = 0; kk < 2; ++kk) {       // local kstep within subtile
        const int ks = half2 * 2 + kk;
        unsigned x0 = cvt_pk_bf16(sv[kk * 8 + 0], sv[kk * 8 + 1]);
        unsigned y0 = cvt_pk_bf16(sv[kk * 8 + 4], sv[kk * 8 + 5]);
        asm volatile("s_nop 0\n\tv_permlane32_swap_b32 %0, %1" : "+v"(x0), "+v"(y0));
        unsigned x1 = cvt_pk_bf16(sv[kk * 8 + 2], sv[kk * 8 + 3]);
        unsigned y1 = cvt_pk_bf16(sv[kk * 8 + 6], sv[kk * 8 + 7]);
        asm volatile("s_nop 0\n\tv_permlane32_swap_b32 %0, %1" : "+v"(x1), "+v"(y1));
        pw[ks][0] = x0; pw[ks][1] = x1; pw[ks][2] = y0; pw[ks][3] = y1;
      }
    }

    // O^T += V^T P^T
    __builtin_amdgcn_s_setprio(1);
#pragma unroll
    for (int ks = 0; ks < 4; ++ks) {
      union { unsigned u[4]; short8 s8; } uu;
      uu.u[0] = pw[ks][0]; uu.u[1] = pw[ks][1]; uu.u[2] = pw[ks][2]; uu.u[3] = pw[ks][3];
      const int c = (ks * 16 + l1 * 8) ^ rswz;
      short8 v0 = *(const short8*)&Vb[l31 * 64 + c];
      short8 v1 = *(const short8*)&Vb[(32 + l31) * 64 + c];
      oa0 = __builtin_amdgcn_mfma_f32_32x32x16_bf16(v0, uu.s8, oa0, 0, 0, 0);
      oa1 = __builtin_amdgcn_mfma_f32_32x32x16_bf16(v1, uu.s8, oa1, 0, 0, 0);
    }
    __builtin_amdgcn_s_setprio(0);
  }

  // ---- store partials: O (unnormalized) + (m,l) per q-row ----
  const size_t row = (size_t)h * T_SEQ + q0 + w * 32 + l31;       // 0..65535
  const size_t obase = ((size_t)half * NH * T_SEQ + row) * 64;
#pragma unroll
  for (int g4 = 0; g4 < 4; ++g4) {
    float4 f0 = {oa0[g4 * 4 + 0], oa0[g4 * 4 + 1], oa0[g4 * 4 + 2], oa0[g4 * 4 + 3]};
    float4 f1 = {oa1[g4 * 4 + 0], oa1[g4 * 4 + 1], oa1[g4 * 4 + 2], oa1[g4 * 4 + 3]};
    *(float4*)&Opart[obase + g4 * 8 + l1 * 4] = f0;
    *(float4*)&Opart[obase + 32 + g4 * 8 + l1 * 4] = f1;
  }
  if (l1 == 0) {
    *(float2*)&MLpart[((size_t)half * NH * T_SEQ + row) * 2] = {m_r, l_r};
  }
}

// ---------------- merge the two KV-half partials -> y bf16 ----------------
// 1024 blocks x 256 thr; 4 threads per q-row (16 d each), 64 rows per block.
__global__ __launch_bounds__(256) void merge_kernel(const float* __restrict__ Opart,
                                                    const float* __restrict__ MLpart,
                                                    short* __restrict__ y) {
  const int tid = threadIdx.x;
  const size_t row = (size_t)blockIdx.x * 64 + (tid >> 2);   // 0..65535 = h*4096+q
  const int dch = (tid & 3) * 16;
  const int h = (int)(row >> 12), q = (int)(row & 4095);
  const float SCL = 0.125f * 1.44269504f;

  const float m0 = MLpart[row * 2], l0 = MLpart[row * 2 + 1];
  const float m1 = MLpart[((size_t)NH * T_SEQ + row) * 2];
  const float l1v = MLpart[((size_t)NH * T_SEQ + row) * 2 + 1];
  const float mm = fmaxf(m0, m1);
  const float a = exp2_fast((m0 - mm) * SCL);
  const float b = exp2_fast((m1 - mm) * SCL);
  const float rl = 1.0f / (l0 * a + l1v * b);
  const float ra = a * rl, rb = b * rl;

  const size_t o0 = row * 64 + dch;
  const size_t o1 = (size_t)NH * T_SEQ * 64 + row * 64 + dch;
  short* yp = y + (size_t)q * C_DIM + h * 64 + dch;
#pragma unroll
  for (int jj = 0; jj < 4; ++jj) {
    float4 p0 = *(const float4*)&Opart[o0 + jj * 4];
    float4 p1 = *(const float4*)&Opart[o1 + jj * 4];
    short4v o;
    o[0] = f2bf(p0.x * ra + p1.x * rb);
    o[1] = f2bf(p0.y * ra + p1.y * rb);
    o[2] = f2bf(p0.z * ra + p1.z * rb);
    o[3] = f2bf(p0.w * ra + p1.w * rb);
    *(short4v*)&yp[jj * 4] = o;
  }
}

extern "C" void kernel_launch(void* const* d_in, const int* in_sizes, int n_in,
                              void* d_out, int out_size, void* d_ws, size_t ws_size,
                              hipStream_t stream) {
  const float* x = (const float*)d_in[0];       // [T, C]
  const float* w_qkv = (const float*)d_in[1];   // [C, 3C]
  const float* w_out = (const float*)d_in[2];   // [C, C]
  float* out = (float*)d_out;                   // [T, C] fp32

  char* ws = (char*)d_ws;
  short* xb = (short*)ws;            ws += (size_t)T_SEQ * C_DIM * 2;       // 8 MB
  short* wqT = (short*)ws;           ws += (size_t)C3 * C_DIM * 2;          // 6 MB
  short* woT = (short*)ws;           ws += (size_t)C_DIM * C_DIM * 2;       // 2 MB
  short* qkv = (short*)ws;           ws += (size_t)T_SEQ * C3 * 2;          // 24 MB
  short* vT = (short*)ws;            ws += (size_t)NH * T_SEQ * HD * 2;     // 8 MB
  short* y = (short*)ws;             ws += (size_t)T_SEQ * C_DIM * 2;       // 8 MB
  float* Opart = (float*)ws;         ws += (size_t)2 * NH * T_SEQ * 64 * 4; // 32 MB
  float* MLpart = (float*)ws;        ws += (size_t)2 * NH * T_SEQ * 2 * 4;  // 1 MB

  // 1. convert inputs to bf16 (weights transposed to [N][K])
  conv_bf16_kernel<<<(T_SEQ * C_DIM) / (256 * 8), 256, 0, stream>>>(x, xb);
  trans_conv_kernel<<<dim3(C3 / 32, C_DIM / 32), dim3(32, 8), 0, stream>>>(w_qkv, wqT, C_DIM, C3);
  trans_conv_kernel<<<dim3(C_DIM / 32, C_DIM / 32), dim3(32, 8), 0, stream>>>(w_out, woT, C_DIM, C_DIM);

  // 2. qkv = x @ w_qkv  (bf16 out)
  gemm_bt_kernel<short><<<dim3(C3 / 128, T_SEQ / 128), 256, 0, stream>>>(xb, wqT, qkv,
                                                                         T_SEQ, C3, C_DIM);
  // 3. repack V -> V^T per head
  repack_v_kernel<<<NH * (T_SEQ / 64), 256, 0, stream>>>(qkv, vT);

  // 4. flash attention partials (2 independent KV halves per q-block)
  attn_kernel<<<1024, 256, 0, stream>>>(qkv, vT, Opart, MLpart);

  // 5. merge halves -> y [T, C] bf16
  merge_kernel<<<1024, 256, 0, stream>>>(Opart, MLpart, y);

  // 6. out = y @ w_out  (fp32 out)
  gemm_bt_kernel<float><<<dim3(C_DIM / 128, T_SEQ / 128), 256, 0, stream>>>(y, woT, out,
                                                                            T_SEQ, C_DIM, C_DIM);
}

// Round 10
// 183.414 us; speedup vs baseline: 1.0308x; 1.0308x over previous
//
#include <hip/hip_runtime.h>
#include <hip/hip_bf16.h>

// Sizes for this problem
#define T_SEQ 4096
#define C_DIM 1024
#define NH    16
#define HD    64
#define C3    3072

typedef __attribute__((ext_vector_type(8))) short short8;
typedef __attribute__((ext_vector_type(4))) short short4v;
typedef __attribute__((ext_vector_type(4))) float f32x4;
typedef __attribute__((ext_vector_type(16))) float f32x16;

__device__ __forceinline__ short f2bf(float f) {
  union { float f; unsigned u; } v; v.f = f;
  unsigned r = v.u + 0x7FFFu + ((v.u >> 16) & 1u);   // round-to-nearest-even
  return (short)(r >> 16);
}

__device__ __forceinline__ unsigned cvt_pk_bf16(float lo, float hi) {
  unsigned r;
  asm volatile("v_cvt_pk_bf16_f32 %0, %1, %2" : "=v"(r) : "v"(lo), "v"(hi));
  return r;
}

// single-instruction 2^x (exp2f w/o fast-math is a multi-inst ocml call)
__device__ __forceinline__ float exp2_fast(float x) {
  return __builtin_amdgcn_exp2f(x);
}

// cross-half (lane^32) max via ds_bpermute-based shfl (proven correct here;
// permlane32_swap-based reduce failed twice — suspected wait-state hazard).
__device__ __forceinline__ float max_half64(float v) {
  return fmaxf(v, __shfl_xor(v, 32, 64));
}

__device__ __forceinline__ float m3(float a, float b, float c) {
  return fmaxf(fmaxf(a, b), c);   // clang fuses to v_max3_f32
}

__device__ __forceinline__ void gld_lds16(const void* g, void* l) {
  __builtin_amdgcn_global_load_lds(
      (const __attribute__((address_space(1))) unsigned int*)g,
      (__attribute__((address_space(3))) unsigned int*)l, 16, 0, 0);
}

// ---------------- fp32 -> bf16 convert (x) ----------------
__global__ __launch_bounds__(256) void conv_bf16_kernel(const float* __restrict__ in,
                                                        short* __restrict__ out) {
  const size_t i = ((size_t)blockIdx.x * 256 + threadIdx.x) * 8;
  float4 v0 = *(const float4*)(in + i);
  float4 v1 = *(const float4*)(in + i + 4);
  short8 o;
  o[0] = f2bf(v0.x); o[1] = f2bf(v0.y); o[2] = f2bf(v0.z); o[3] = f2bf(v0.w);
  o[4] = f2bf(v1.x); o[5] = f2bf(v1.y); o[6] = f2bf(v1.z); o[7] = f2bf(v1.w);
  *(short8*)(out + i) = o;
}

// ---------------- fp32 [K][N] -> bf16 [N][K] transpose-convert ----------------
__global__ void trans_conv_kernel(const float* __restrict__ in, short* __restrict__ out,
                                  int K, int N) {
  __shared__ float t[32][33];
  const int n0 = blockIdx.x * 32, k0 = blockIdx.y * 32;
  const int tx = threadIdx.x, ty = threadIdx.y;
  for (int i = ty; i < 32; i += 8) t[i][tx] = in[(size_t)(k0 + i) * N + n0 + tx];
  __syncthreads();
  for (int i = ty; i < 32; i += 8) out[(size_t)(n0 + i) * K + k0 + tx] = f2bf(t[tx][i]);
}

// ---------------- bf16 GEMM: C[M,N] = A[M,K] * BT[N,K]^T ----------------
__device__ __forceinline__ void store_out(short* C, size_t idx, float v) { C[idx] = f2bf(v); }
__device__ __forceinline__ void store_out(float* C, size_t idx, float v) { C[idx] = v; }

template <typename OutT>
__global__ __launch_bounds__(256) void gemm_bt_kernel(const short* __restrict__ A,
                                                      const short* __restrict__ BT,
                                                      OutT* __restrict__ C,
                                                      int M, int N, int K) {
  __shared__ __align__(16) short As[128 * 32];
  __shared__ __align__(16) short Bs[128 * 32];
  const int tid = threadIdx.x;
  const int wid = tid >> 6;
  const int lane = tid & 63;
  const int l15 = lane & 15;
  const int l4 = lane >> 4;
  const int wr = wid >> 1;
  const int wc = wid & 1;
  const int bm = blockIdx.y * 128;
  const int bn = blockIdx.x * 128;

  f32x4 acc[4][4];
#pragma unroll
  for (int m = 0; m < 4; ++m)
#pragma unroll
    for (int n = 0; n < 4; ++n) acc[m][n] = (f32x4){0.f, 0.f, 0.f, 0.f};

  const int ebase = wid * 1024;              // 1024 bf16 elements per wave (2 x 512)
  const int e0 = ebase + lane * 8;
  const int r0 = e0 >> 5, c0 = e0 & 31;
  const int r1 = r0 + 16;                    // e0 + 512

  for (int k0 = 0; k0 < K; k0 += 32) {
    __syncthreads();
    gld_lds16(A + (size_t)(bm + r0) * K + k0 + c0, As + ebase);
    gld_lds16(A + (size_t)(bm + r1) * K + k0 + c0, As + ebase + 512);
    gld_lds16(BT + (size_t)(bn + r0) * K + k0 + c0, Bs + ebase);
    gld_lds16(BT + (size_t)(bn + r1) * K + k0 + c0, Bs + ebase + 512);
    __syncthreads();

    short8 a[4], b[4];
#pragma unroll
    for (int m = 0; m < 4; ++m)
      a[m] = *(const short8*)&As[(wr * 64 + m * 16 + l15) * 32 + l4 * 8];
#pragma unroll
    for (int n = 0; n < 4; ++n)
      b[n] = *(const short8*)&Bs[(wc * 64 + n * 16 + l15) * 32 + l4 * 8];
#pragma unroll
    for (int m = 0; m < 4; ++m)
#pragma unroll
      for (int n = 0; n < 4; ++n)
        acc[m][n] = __builtin_amdgcn_mfma_f32_16x16x32_bf16(a[m], b[n], acc[m][n], 0, 0, 0);
  }

#pragma unroll
  for (int m = 0; m < 4; ++m) {
    const int row0 = bm + wr * 64 + m * 16 + l4 * 4;
#pragma unroll
    for (int n = 0; n < 4; ++n) {
      const int col = bn + wc * 64 + n * 16 + l15;
#pragma unroll
      for (int r = 0; r < 4; ++r)
        store_out(C, (size_t)(row0 + r) * N + col, acc[m][n][r]);
    }
  }
}

// ---------------- repack V: qkv[t][2048 + h*64 + d] -> vT[h][d][t] ----------------
__global__ __launch_bounds__(256) void repack_v_kernel(const short* __restrict__ qkv,
                                                       short* __restrict__ vT) {
  const int h = blockIdx.x >> 6;
  const int t0 = (blockIdx.x & 63) << 6;
  __shared__ __align__(16) short tile[64][72];
  const int t = threadIdx.x;
  const int r = t >> 3, c = (t & 7) << 3;
#pragma unroll
  for (int i = 0; i < 2; ++i) {
    const int rr = r + i * 32;
    *(short8*)&tile[rr][c] =
        *(const short8*)&qkv[(size_t)(t0 + rr) * C3 + 2048 + h * 64 + c];
  }
  __syncthreads();
  const int d = t >> 3, tt = (t & 7) << 3;
#pragma unroll
  for (int i = 0; i < 2; ++i) {
    const int dd = d + i * 32;
    short8 v;
#pragma unroll
    for (int j = 0; j < 8; ++j) v[j] = tile[tt + j][dd];
    *(short8*)&vT[(size_t)(h * 64 + dd) * T_SEQ + t0 + tt] = v;
  }
}

// ---------------- flash attention: 32x32 MFMA, in-reg P, KV-split, counted-vmcnt ----------------
// 512 blocks x 512 threads. 8 waves = 2 groups of 4; group g covers KV half g.
// l computed via ones-row MFMA (no sum tree/shfl); max-shfl only inside rare rescale branch.
__global__ __launch_bounds__(512, 4) void attn_kernel(const short* __restrict__ qkv,
                                                      const short* __restrict__ vT,
                                                      short* __restrict__ y) {
  // XCD-aware: heads {2x, 2x+1} -> XCD x (round-robin bid%8 assumption)
  const int bid = blockIdx.x;
  const int xcd = bid & 7, slot = bid >> 3;      // slot 0..63
  const int h = xcd * 2 + (slot >> 5);
  const int q0 = (slot & 31) * 128;

  const int tid = threadIdx.x;
  const int w = tid >> 6, lane = tid & 63, l31 = lane & 31, l1 = lane >> 5;
  const int g = w >> 2, wg = w & 3;
  const int kvbase = g * (T_SEQ / 2);

  __shared__ __align__(16) short Ks[2][2][4096];   // [group][dbuf][kv*64+d], d-swizzled
  __shared__ __align__(16) short Vs[2][2][4096];   // [group][dbuf][d*64+kv], kv-swizzled

  // Q B-fragments: col q = l31, k = d = ks*16 + l1*8 + j
  short8 qf[4];
  {
    const short* qp = qkv + (size_t)(q0 + wg * 32 + l31) * C3 + h * 64 + l1 * 8;
#pragma unroll
    for (int ks = 0; ks < 4; ++ks) qf[ks] = *(const short8*)(qp + ks * 16);
  }

  // ones A-fragment: conceptual 32x64 tile with rows 0 and 4 = 1.0 (others 0).
  // acc row d' = (r&3)+8*(r>>2)+4*l1 -> reg 0 holds row 0 (l1=0) / row 4 (l1=1):
  // both ones -> oext[0] = sum_kv P[q][kv] = l, identical in every lane of the q-column.
  short8 ones_frag;
  {
    const short ob = (l31 == 0 || l31 == 4) ? (short)0x3F80 : (short)0;
#pragma unroll
    for (int j = 0; j < 8; ++j) ones_frag[j] = ob;
  }

  f32x16 oa0, oa1, oext;   // O^T: col q=l31, row d=(r&3)+8*(r>>2)+4*l1 (+32 for oa1)
#pragma unroll
  for (int r = 0; r < 16; ++r) { oa0[r] = 0.f; oa1[r] = 0.f; oext[r] = 0.f; }
  float m_r = -INFINITY;
  const float SCL = 0.125f * 1.44269504f;          // 1/sqrt(64) * log2(e)
  const float TH = 8.0f / SCL;                     // defer-max threshold (p <= 2^8)

  // staging: row lr0 = wg*8 + (lane>>3) (+32 for i=1), source col pre-swizzled.
  const int lr0 = wg * 8 + (lane >> 3);
  const int csw = ((lane & 7) << 3) ^ ((lane >> 3) << 3);   // shorts
  const short* kpt = qkv + 1024 + h * 64 + csw + (size_t)(kvbase + lr0) * C3;
  const short* vpt = vT + (size_t)(h * 64 + lr0) * T_SEQ + csw + kvbase;
  const int rswz = (l31 & 7) << 3;

  auto stage = [&](int buf) {
#pragma unroll
    for (int i = 0; i < 2; ++i) {
      gld_lds16(kpt + (size_t)i * 32 * C3, &Ks[g][buf][i * 2048 + wg * 512]);
      gld_lds16(vpt + (size_t)i * 32 * T_SEQ, &Vs[g][buf][i * 2048 + wg * 512]);
    }
  };

  stage(0);
  kpt += (size_t)64 * C3;
  vpt += 64;

  const int NT = T_SEQ / 2 / 64;   // 32 tiles per group
  for (int t = 0; t < NT; ++t) {
    const int cur = t & 1;
    // barrier 1: everyone done READING buf cur^1 (tile t-1) -> safe to overwrite
    __builtin_amdgcn_s_barrier();
    if (t + 1 < NT) {
      stage(cur ^ 1);
      kpt += (size_t)64 * C3;
      vpt += 64;
      asm volatile("s_waitcnt vmcnt(4)" ::: "memory");   // tile t's 4 loads landed; t+1's fly
    } else {
      asm volatile("s_waitcnt vmcnt(0)" ::: "memory");   // last tile: full drain
    }
    // barrier 2: everyone's tile-t data is in LDS
    __builtin_amdgcn_s_barrier();

    const short* Kb = &Ks[g][cur][0];
    const short* Vb = &Vs[g][cur][0];

    // S^T = K Q^T: two 32-kv subtiles
    f32x16 s0, s1;
#pragma unroll
    for (int r = 0; r < 16; ++r) { s0[r] = 0.f; s1[r] = 0.f; }
    __builtin_amdgcn_s_setprio(1);
#pragma unroll
    for (int ks = 0; ks < 4; ++ks) {
      const int c = (ks * 16 + l1 * 8) ^ rswz;
      short8 k0 = *(const short8*)&Kb[l31 * 64 + c];
      short8 k1 = *(const short8*)&Kb[(32 + l31) * 64 + c];
      s0 = __builtin_amdgcn_mfma_f32_32x32x16_bf16(k0, qf[ks], s0, 0, 0, 0);
      s1 = __builtin_amdgcn_mfma_f32_32x32x16_bf16(k1, qf[ks], s1, 0, 0, 0);
    }
    __builtin_amdgcn_s_setprio(0);

    // lane-local tile max via max3 tree (no cross-lane shfl on the common path)
    float tm;
    {
      float v0 = m3(s0[0], s0[1], s0[2]);
      float v1 = m3(s0[3], s0[4], s0[5]);
      float v2 = m3(s0[6], s0[7], s0[8]);
      float v3 = m3(s0[9], s0[10], s0[11]);
      float v4 = m3(s0[12], s0[13], s0[14]);
      float v5 = fmaxf(s0[15], s1[0]);
      float v6 = m3(s1[1], s1[2], s1[3]);
      float v7 = m3(s1[4], s1[5], s1[6]);
      float v8 = m3(s1[7], s1[8], s1[9]);
      float v9 = m3(s1[10], s1[11], s1[12]);
      float v10 = m3(s1[13], s1[14], s1[15]);
      float w0 = m3(v0, v1, v2);
      float w1 = m3(v3, v4, v5);
      float w2 = m3(v6, v7, v8);
      float w3 = fmaxf(v9, v10);
      tm = fmaxf(m3(w0, w1, w2), w3);
    }

    // defer-max: __any spans all 64 lanes, so the decision (and m_r) stays
    // consistent across both lane-halves; the cross-half max runs only here.
    if (__any(tm > m_r + TH)) {
      const float tmx = max_half64(tm);
      const float mn = fmaxf(m_r, tmx);
      const float al = exp2_fast((m_r - mn) * SCL);
      m_r = mn;
#pragma unroll
      for (int r = 0; r < 16; ++r) { oa0[r] *= al; oa1[r] *= al; }
      oext[0] *= al;                       // l lives in oext[0]
    }
    const float msc = m_r * SCL;
#pragma unroll
    for (int r = 0; r < 16; ++r) s0[r] = exp2_fast(fmaf(s0[r], SCL, -msc));
#pragma unroll
    for (int r = 0; r < 16; ++r) s1[r] = exp2_fast(fmaf(s1[r], SCL, -msc));

    // P -> B-fragments in-register: cvt_pk + permlane32_swap (T12).
    // s_nop guards the VALU-write->permlane-read wait-state hazard (opaque to compiler).
    unsigned pw[4][4];
#pragma unroll
    for (int half = 0; half < 2; ++half) {
      const f32x16& sv = half ? s1 : s0;
#pragma unroll
      for (int kk = 0; kk < 2; ++kk) {       // local kstep within subtile
        const int ks = half * 2 + kk;
        unsigned x0 = cvt_pk_bf16(sv[kk * 8 + 0], sv[kk * 8 + 1]);
        unsigned y0 = cvt_pk_bf16(sv[kk * 8 + 4], sv[kk * 8 + 5]);
        asm volatile("s_nop 0\n\tv_permlane32_swap_b32 %0, %1" : "+v"(x0), "+v"(y0));
        unsigned x1 = cvt_pk_bf16(sv[kk * 8 + 2], sv[kk * 8 + 3]);
        unsigned y1 = cvt_pk_bf16(sv[kk * 8 + 6], sv[kk * 8 + 7]);
        asm volatile("s_nop 0\n\tv_permlane32_swap_b32 %0, %1" : "+v"(x1), "+v"(y1));
        pw[ks][0] = x0; pw[ks][1] = x1; pw[ks][2] = y0; pw[ks][3] = y1;
      }
    }

    // O^T += V^T P^T ; l += ones-row . P (oext[0])
    __builtin_amdgcn_s_setprio(1);
#pragma unroll
    for (int ks = 0; ks < 4; ++ks) {
      union { unsigned u[4]; short8 s8; } uu;
      uu.u[0] = pw[ks][0]; uu.u[1] = pw[ks][1]; uu.u[2] = pw[ks][2]; uu.u[3] = pw[ks][3];
      const int c = (ks * 16 + l1 * 8) ^ rswz;
      short8 v0 = *(const short8*)&Vb[l31 * 64 + c];
      short8 v1 = *(const short8*)&Vb[(32 + l31) * 64 + c];
      oa0 = __builtin_amdgcn_mfma_f32_32x32x16_bf16(v0, uu.s8, oa0, 0, 0, 0);
      oa1 = __builtin_amdgcn_mfma_f32_32x32x16_bf16(v1, uu.s8, oa1, 0, 0, 0);
      oext = __builtin_amdgcn_mfma_f32_32x32x16_bf16(ones_frag, uu.s8, oext, 0, 0, 0);
    }
    __builtin_amdgcn_s_setprio(0);
  }

  const float l_r = oext[0];

  // ---- merge the two KV halves (exact online-softmax combine), then store ----
  __syncthreads();                          // all K/V LDS use done (full drain OK here)
  float* Oex = (float*)&Vs[0][0][0];        // [r<32][slot<256], conflict-free
  float* mex = (float*)&Ks[0][0][0];        // [2][slot<256]
  const int xslot = wg * 64 + lane;         // 0..255 within group
  if (g == 1) {
#pragma unroll
    for (int r = 0; r < 16; ++r) {
      Oex[r * 256 + xslot] = oa0[r];
      Oex[(16 + r) * 256 + xslot] = oa1[r];
    }
    mex[xslot] = m_r;
    mex[256 + xslot] = l_r;
  }
  __syncthreads();
  if (g == 0) {
    const float m_b = mex[xslot], l_b = mex[256 + xslot];
    const float mm = fmaxf(m_r, m_b);
    const float a = exp2_fast((m_r - mm) * SCL);
    const float b = exp2_fast((m_b - mm) * SCL);
    const float rl = 1.0f / (l_r * a + l_b * b);
    const float ra = a * rl, rb = b * rl;
    const size_t yb = (size_t)(q0 + wg * 32 + l31) * C_DIM + h * 64;
#pragma unroll
    for (int g4 = 0; g4 < 4; ++g4) {
      short4v o0, o1;
#pragma unroll
      for (int j = 0; j < 4; ++j) {
        o0[j] = f2bf(oa0[g4 * 4 + j] * ra + Oex[(g4 * 4 + j) * 256 + xslot] * rb);
        o1[j] = f2bf(oa1[g4 * 4 + j] * ra + Oex[(16 + g4 * 4 + j) * 256 + xslot] * rb);
      }
      *(short4v*)&y[yb + g4 * 8 + l1 * 4] = o0;
      *(short4v*)&y[yb + 32 + g4 * 8 + l1 * 4] = o1;
    }
  }
}

extern "C" void kernel_launch(void* const* d_in, const int* in_sizes, int n_in,
                              void* d_out, int out_size, void* d_ws, size_t ws_size,
                              hipStream_t stream) {
  const float* x = (const float*)d_in[0];       // [T, C]
  const float* w_qkv = (const float*)d_in[1];   // [C, 3C]
  const float* w_out = (const float*)d_in[2];   // [C, C]
  float* out = (float*)d_out;                   // [T, C] fp32

  char* ws = (char*)d_ws;
  short* xb = (short*)ws;            ws += (size_t)T_SEQ * C_DIM * 2;       // 8 MB
  short* wqT = (short*)ws;           ws += (size_t)C3 * C_DIM * 2;          // 6 MB
  short* woT = (short*)ws;           ws += (size_t)C_DIM * C_DIM * 2;       // 2 MB
  short* qkv = (short*)ws;           ws += (size_t)T_SEQ * C3 * 2;          // 24 MB
  short* vT = (short*)ws;            ws += (size_t)NH * T_SEQ * HD * 2;     // 8 MB
  short* y = (short*)ws;             ws += (size_t)T_SEQ * C_DIM * 2;       // 8 MB

  // 1. convert inputs to bf16 (weights transposed to [N][K])
  conv_bf16_kernel<<<(T_SEQ * C_DIM) / (256 * 8), 256, 0, stream>>>(x, xb);
  trans_conv_kernel<<<dim3(C3 / 32, C_DIM / 32), dim3(32, 8), 0, stream>>>(w_qkv, wqT, C_DIM, C3);
  trans_conv_kernel<<<dim3(C_DIM / 32, C_DIM / 32), dim3(32, 8), 0, stream>>>(w_out, woT, C_DIM, C_DIM);

  // 2. qkv = x @ w_qkv  (bf16 out)
  gemm_bt_kernel<short><<<dim3(C3 / 128, T_SEQ / 128), 256, 0, stream>>>(xb, wqT, qkv,
                                                                         T_SEQ, C3, C_DIM);
  // 3. repack V -> V^T per head
  repack_v_kernel<<<NH * (T_SEQ / 64), 256, 0, stream>>>(qkv, vT);

  // 4. flash attention -> y [T, C] bf16
  attn_kernel<<<512, 512, 0, stream>>>(qkv, vT, y);

  // 5. out = y @ w_out  (fp32 out)
  gemm_bt_kernel<float><<<dim3(C_DIM / 128, T_SEQ / 128), 256, 0, stream>>>(y, woT, out,
                                                                            T_SEQ, C_DIM, C_DIM);
}